// Round 2
// baseline (663.283 us; speedup 1.0000x reference)
//
#include <hip/hip_runtime.h>

typedef __attribute__((ext_vector_type(8))) short s16x8;
typedef __attribute__((ext_vector_type(4))) float f32x4;
typedef __attribute__((ext_vector_type(16))) float f32x16;
typedef __attribute__((ext_vector_type(2))) unsigned int u32x2;

#define DEV static __device__ __forceinline__

// async global->LDS, 16B per lane. LDS dest must be uniform base + lane*16.
DEV void gload_lds16(const void* g, void* l) {
  __builtin_amdgcn_global_load_lds(
      (const __attribute__((address_space(1))) void*)g,
      (__attribute__((address_space(3))) void*)l, 16, 0, 0);
}

DEV unsigned short f2bf(float f) {  // RNE float->bf16 (no NaN inputs here)
  unsigned int u = __float_as_uint(f);
  u = (u + 0x7fffu + ((u >> 16) & 1u)) >> 16;
  return (unsigned short)u;
}

DEV unsigned pk2(float lo, float hi) {  // pack 2 f32 -> 2 bf16 in one VALU op
  unsigned r;
  asm("v_cvt_pk_bf16_f32 %0, %1, %2" : "=v"(r) : "v"(lo), "v"(hi));
  return r;
}

// ---------------- fp32 -> bf16 conversion ----------------
DEV void cvt8(const float* __restrict__ in, unsigned short* __restrict__ out, int i) {
  float4 a = *(const float4*)(in + i);
  float4 b = *(const float4*)(in + i + 4);
  union { s16x8 v; unsigned short u[8]; } o;
  o.u[0] = f2bf(a.x); o.u[1] = f2bf(a.y); o.u[2] = f2bf(a.z); o.u[3] = f2bf(a.w);
  o.u[4] = f2bf(b.x); o.u[5] = f2bf(b.y); o.u[6] = f2bf(b.z); o.u[7] = f2bf(b.w);
  *(s16x8*)(out + i) = o.v;
}

__global__ __launch_bounds__(256) void k_cvt(const float* __restrict__ in,
                                             unsigned short* __restrict__ out) {
  cvt8(in, out, (blockIdx.x * 256 + threadIdx.x) * 8);
}

__global__ __launch_bounds__(256) void k_cvt4(
    const float* __restrict__ a0, const float* __restrict__ a1,
    const float* __restrict__ a2, const float* __restrict__ a3,
    unsigned short* __restrict__ o0, unsigned short* __restrict__ o1,
    unsigned short* __restrict__ o2, unsigned short* __restrict__ o3) {
  const float* in; unsigned short* out;
  switch (blockIdx.y) {
    case 0: in = a0; out = o0; break;
    case 1: in = a1; out = o1; break;
    case 2: in = a2; out = o2; break;
    default: in = a3; out = o3; break;
  }
  cvt8(in, out, (blockIdx.x * 256 + threadIdx.x) * 8);
}

// ---------------- NT GEMM: C[M,N] = A[M,K] * W[N,K]^T + bias ----------------
template <int MODE>
__global__ __launch_bounds__(256) void k_gemm(
    const unsigned short* __restrict__ A,
    const unsigned short* __restrict__ B0, const unsigned short* __restrict__ B1,
    const unsigned short* __restrict__ B2,
    const float* __restrict__ bias0, const float* __restrict__ bias1,
    const float* __restrict__ bias2,
    void* __restrict__ out0, void* __restrict__ out1, void* __restrict__ out2) {
  constexpr int K = 1024;
  __shared__ unsigned short As[128 * 64];
  __shared__ unsigned short Bs[128 * 64];

  const int z = blockIdx.z;
  const unsigned short* Bw = (z == 0) ? B0 : (z == 1) ? B1 : B2;
  const float* bias = (z == 0) ? bias0 : (z == 1) ? bias1 : bias2;
  void* outp = (z == 0) ? out0 : (z == 1) ? out1 : out2;

  const int tid = threadIdx.x;
  const int lane = tid & 63;
  const int l15 = lane & 15, g = lane >> 4;
  const int w = tid >> 6;
  const int wr = w >> 1, wc = w & 1;
  const int m0 = blockIdx.y * 128;
  const int n0 = blockIdx.x * 128;

  const int sr = tid >> 3;
  const int sc = tid & 7;

  f32x4 acc[4][4] = {};

  for (int kt = 0; kt < K / 64; ++kt) {
#pragma unroll
    for (int i = 0; i < 4; ++i) {
      const int row = i * 32 + sr;
      gload_lds16(A + (size_t)(m0 + row) * K + kt * 64 + ((sc ^ (row & 7)) * 8),
                  (void*)(As + i * 2048 + tid * 8));
      gload_lds16(Bw + (size_t)(n0 + row) * K + kt * 64 + ((sc ^ (row & 7)) * 8),
                  (void*)(Bs + i * 2048 + tid * 8));
    }
    __syncthreads();
#pragma unroll
    for (int ks = 0; ks < 2; ++ks) {
      s16x8 af[4], bf[4];
#pragma unroll
      for (int i = 0; i < 4; ++i) {
        const int ra = wr * 64 + i * 16 + l15;
        af[i] = *(const s16x8*)(As + ra * 64 + (((ks * 4 + g) ^ (ra & 7)) * 8));
        const int rb = wc * 64 + i * 16 + l15;
        bf[i] = *(const s16x8*)(Bs + rb * 64 + (((ks * 4 + g) ^ (rb & 7)) * 8));
      }
#pragma unroll
      for (int i = 0; i < 4; ++i)
#pragma unroll
        for (int j = 0; j < 4; ++j)
          acc[i][j] = __builtin_amdgcn_mfma_f32_16x16x32_bf16(af[i], bf[j], acc[i][j], 0, 0, 0);
    }
    __syncthreads();
  }

#pragma unroll
  for (int j = 0; j < 4; ++j) {
    const int gcol = n0 + wc * 64 + j * 16 + l15;
    const float bv = bias[gcol];
#pragma unroll
    for (int i = 0; i < 4; ++i) {
#pragma unroll
      for (int r = 0; r < 4; ++r) {
        const int grow = m0 + wr * 64 + i * 16 + g * 4 + r;
        const float val = acc[i][j][r] + bv;
        if (MODE == 0) {
          const int bb = grow >> 11, s = grow & 2047;
          const int h = gcol >> 6, d = gcol & 63;
          ((unsigned short*)outp)[(((size_t)(bb * 16 + h) * 2048 + s) << 6) + d] = f2bf(val);
        } else {
          ((float*)outp)[(size_t)grow * 1024 + gcol] = val;
        }
      }
    }
  }
}

// ---------------- V transpose: [B,H,S,dk] -> [B,H,dk,S] ----------------
__global__ __launch_bounds__(256) void k_transpose(const unsigned short* __restrict__ v,
                                                   unsigned short* __restrict__ vt) {
  __shared__ unsigned short T[64 * 72];
  const int t = threadIdx.x;
  const size_t base = (size_t)(blockIdx.z * 16 + blockIdx.y) * 2048 * 64;
  const int s0 = blockIdx.x * 64;
  {
    const int srow = t >> 2, dc = (t & 3) * 16;
    const unsigned short* src = v + base + (size_t)(s0 + srow) * 64 + dc;
    *(s16x8*)(T + srow * 72 + dc) = *(const s16x8*)src;
    *(s16x8*)(T + srow * 72 + dc + 8) = *(const s16x8*)(src + 8);
  }
  __syncthreads();
  {
    const int drow = t >> 2, scc = (t & 3) * 16;
    union { s16x8 v8; unsigned short u[8]; } o0, o1;
#pragma unroll
    for (int e = 0; e < 8; ++e) o0.u[e] = T[(scc + e) * 72 + drow];
#pragma unroll
    for (int e = 0; e < 8; ++e) o1.u[e] = T[(scc + 8 + e) * 72 + drow];
    unsigned short* dst = vt + base + (size_t)drow * 2048 + s0 + scc;
    *(s16x8*)dst = o0.v8;
    *(s16x8*)(dst + 8) = o1.v8;
  }
}

// ---------------- mask transpose: mask[b][q][kv] f32 -> maskT[bz][kv][q] bf16 ----------------
// pre-scaled by 1/sqrt(dk) = 0.125
__global__ __launch_bounds__(256) void k_maskT(const float* __restrict__ mask,
                                               unsigned short* __restrict__ mT, int b0) {
  __shared__ unsigned short T[64][65];
  const int t = threadIdx.x;
  const int bz = blockIdx.z;
  const float* mb = mask + (size_t)(b0 + bz) * 2048 * 2048;
  unsigned short* ob = mT + (size_t)bz * 2048 * 2048;
  const int q0 = blockIdx.y * 64, k0 = blockIdx.x * 64;
  const int r = t >> 2, c4 = (t & 3) * 16;
  {
    const float* src = mb + (size_t)(q0 + r) * 2048 + k0 + c4;
#pragma unroll
    for (int i = 0; i < 16; i += 4) {
      float4 v = *(const float4*)(src + i);
      T[r][c4 + i + 0] = f2bf(v.x * 0.125f);
      T[r][c4 + i + 1] = f2bf(v.y * 0.125f);
      T[r][c4 + i + 2] = f2bf(v.z * 0.125f);
      T[r][c4 + i + 3] = f2bf(v.w * 0.125f);
    }
  }
  __syncthreads();
  {
    union { s16x8 v8; unsigned short u[8]; } o0, o1;
#pragma unroll
    for (int e = 0; e < 8; ++e) o0.u[e] = T[c4 + e][r];
#pragma unroll
    for (int e = 0; e < 8; ++e) o1.u[e] = T[c4 + 8 + e][r];
    unsigned short* dst = ob + (size_t)(k0 + r) * 2048 + q0 + c4;
    *(s16x8*)dst = o0.v8;
    *(s16x8*)(dst + 8) = o1.v8;
  }
}

// ---------------- flash attention, swapped-QK^T 32x32 structure ----------------
// grid (H=16, S/128=16, 2 batches), 256 threads = 4 waves, each wave owns 32 q-rows.
// S^T = mfma_32x32x16(K, Q): lane holds q = q0w + (lane&31); kv = 32f + (r&3)+8*(r>>2)+4*(lane>>5).
// Softmax lane-local; P->B-frag via cvt_pk + permlane32_swap (T12); PV: O^T = mfma(V^T, P^T).
__global__ __launch_bounds__(256) void k_attn2(
    const unsigned short* __restrict__ q, const unsigned short* __restrict__ k,
    const unsigned short* __restrict__ vt, const unsigned short* __restrict__ mT,
    unsigned short* __restrict__ concat, int b0) {
  __shared__ unsigned short Ks[2][64 * 64];   // [kv][d], chunk-swizzled
  __shared__ unsigned short Vs[2][64 * 64];   // [d][kv], chunk-swizzled

  const int tid = threadIdx.x;
  const int lane = tid & 63;
  const int w = tid >> 6;
  const int l31 = lane & 31;
  const int hh = lane >> 5;
  const int h = blockIdx.x, qt = blockIdx.y, bz = blockIdx.z;
  const int b = b0 + bz;

  const size_t bhO = (size_t)(b * 16 + h) * (2048 * 64);
  const unsigned short* kb = k + bhO;
  const unsigned short* vb = vt + bhO;
  const int qg = qt * 128 + w * 32 + l31;   // this lane's q row

  // Q B-fragments: qf[kd] holds Q[qg][kd*16 + hh*8 + i]
  s16x8 qf[4];
  {
    const unsigned short* qp = q + bhO + (size_t)qg * 64 + hh * 8;
#pragma unroll
    for (int kd = 0; kd < 4; ++kd) qf[kd] = *(const s16x8*)(qp + kd * 16);
  }
  const unsigned short* mrow = mT + (size_t)bz * (2048 * 2048) + qg;

  float m_r = -3.0e38f, l_r = 0.f;
  f32x16 oacc[2] = {};

  const int sr = tid >> 3;  // 0..31
  const int sc = tid & 7;

  // stage tile 0 into buf 0
#pragma unroll
  for (int i = 0; i < 2; ++i) {
    const int row = i * 32 + sr;
    const int sz = (sc ^ (row & 7)) * 8;
    gload_lds16(kb + (size_t)row * 64 + sz, (void*)(Ks[0] + i * 2048 + tid * 8));
    gload_lds16(vb + (size_t)row * 2048 + sz, (void*)(Vs[0] + i * 2048 + tid * 8));
  }
  __syncthreads();  // compiler-emitted vmcnt(0) drains the stage

  for (int t = 0; t < 32; ++t) {
    const int cur = t & 1;
    const unsigned short* Kc = Ks[cur];
    const unsigned short* Vc = Vs[cur];
    if (t < 31) {
      const int kv0n = (t + 1) * 64;
#pragma unroll
      for (int i = 0; i < 2; ++i) {
        const int row = i * 32 + sr;
        const int sz = (sc ^ (row & 7)) * 8;
        gload_lds16(kb + (size_t)(kv0n + row) * 64 + sz,
                    (void*)(Ks[cur ^ 1] + i * 2048 + tid * 8));
        gload_lds16(vb + (size_t)row * 2048 + kv0n + sz,
                    (void*)(Vs[cur ^ 1] + i * 2048 + tid * 8));
      }
    }
    // QK^T -> S^T [64 kv][32 q]
    f32x16 sacc[2] = {};
    __builtin_amdgcn_s_setprio(1);
#pragma unroll
    for (int f = 0; f < 2; ++f) {
      const int rk = f * 32 + l31;
      const unsigned short* Kr = Kc + rk * 64;
      const int swb = rk & 7;
#pragma unroll
      for (int kd = 0; kd < 4; ++kd) {
        const s16x8 kf = *(const s16x8*)(Kr + (((kd * 2 + hh) ^ swb) * 8));
        sacc[f] = __builtin_amdgcn_mfma_f32_32x32x16_bf16(kf, qf[kd], sacc[f], 0, 0, 0);
      }
    }
    __builtin_amdgcn_s_setprio(0);

    // mask (pre-scaled bf16, transposed) + online softmax, all lane-local
    const int kv0 = t * 64;
    float p[32];
    float tm = -3.0e38f;
#pragma unroll
    for (int f = 0; f < 2; ++f)
#pragma unroll
      for (int r = 0; r < 16; ++r) {
        const int kvrel = f * 32 + (r & 3) + 8 * (r >> 2) + 4 * hh;
        const float mval =
            __uint_as_float((unsigned)mrow[(size_t)(kv0 + kvrel) * 2048] << 16);
        const float sv = sacc[f][r] * mval;
        p[f * 16 + r] = sv;
        tm = fmaxf(tm, sv);
      }
    tm = fmaxf(tm, __shfl_xor(tm, 32, 64));
    if (__any(tm > m_r + 8.0f)) {  // T13 defer-max: rescale pass is rare
      const float mn = fmaxf(m_r, tm);
      const float rs = __expf(m_r - mn);
      m_r = mn;
      l_r *= rs;
#pragma unroll
      for (int df = 0; df < 2; ++df)
#pragma unroll
        for (int r = 0; r < 16; ++r) oacc[df][r] *= rs;
    }
    float ps = 0.f;
#pragma unroll
    for (int n = 0; n < 32; ++n) {
      p[n] = __expf(p[n] - m_r);
      ps += p[n];
    }
    ps += __shfl_xor(ps, 32, 64);
    l_r += ps;

    // P^T -> bf16 B-frags (T12) + PV: oacc[df] += V^T * P^T
#pragma unroll
    for (int ks = 0; ks < 4; ++ks) {
      const int pb = ks * 8;
      const unsigned X0 = pk2(p[pb + 0], p[pb + 1]);
      const unsigned X1 = pk2(p[pb + 2], p[pb + 3]);
      const unsigned Y0 = pk2(p[pb + 4], p[pb + 5]);
      const unsigned Y1 = pk2(p[pb + 6], p[pb + 7]);
      const u32x2 r0 = __builtin_amdgcn_permlane32_swap(X0, Y0, false, false);
      const u32x2 r1 = __builtin_amdgcn_permlane32_swap(X1, Y1, false, false);
      union { s16x8 v; unsigned u[4]; } pf;
      pf.u[0] = r0.x; pf.u[1] = r1.x; pf.u[2] = r0.y; pf.u[3] = r1.y;
#pragma unroll
      for (int df = 0; df < 2; ++df) {
        const int rv = df * 32 + l31;
        const s16x8 vf =
            *(const s16x8*)(Vc + rv * 64 + (((ks * 2 + hh) ^ (rv & 7)) * 8));
        oacc[df] = __builtin_amdgcn_mfma_f32_32x32x16_bf16(vf, pf.v, oacc[df], 0, 0, 0);
      }
    }
    __syncthreads();  // drains vmcnt (stage) + lgkm; protects both buffers
  }

  // normalize + write concat [B,S,H*dk] bf16 (paired 4B stores)
  const float inv = 1.0f / l_r;
  unsigned short* cb = concat + ((size_t)b * 2048 + qg) * 1024 + h * 64;
#pragma unroll
  for (int df = 0; df < 2; ++df)
#pragma unroll
    for (int r = 0; r < 16; r += 2) {
      const int d = df * 32 + (r & 3) + 8 * (r >> 2) + 4 * hh;
      const unsigned u = (unsigned)f2bf(oacc[df][r] * inv) |
                         ((unsigned)f2bf(oacc[df][r + 1] * inv) << 16);
      *(unsigned*)(cb + d) = u;
    }
}

// ---------------- launch ----------------
extern "C" void kernel_launch(void* const* d_in, const int* in_sizes, int n_in,
                              void* d_out, int out_size, void* d_ws, size_t ws_size,
                              hipStream_t stream) {
  const float* x    = (const float*)d_in[0];
  const float* mask = (const float*)d_in[1];
  const float* Wq   = (const float*)d_in[2];
  const float* bq   = (const float*)d_in[3];
  const float* Wk   = (const float*)d_in[4];
  const float* bk   = (const float*)d_in[5];
  const float* Wv   = (const float*)d_in[6];
  const float* bv   = (const float*)d_in[7];
  const float* Wo   = (const float*)d_in[8];
  const float* bo   = (const float*)d_in[9];

  char* ws = (char*)d_ws;
  unsigned short* xb  = (unsigned short*)(ws);                        // 16 MB (x bf16; later aliased by concat)
  unsigned short* wqb = (unsigned short*)(ws + (size_t)16777216);     // 2 MB each
  unsigned short* wkb = (unsigned short*)(ws + (size_t)18874368);
  unsigned short* wvb = (unsigned short*)(ws + (size_t)20971520);
  unsigned short* wob = (unsigned short*)(ws + (size_t)23068672);
  unsigned short* qw  = (unsigned short*)(ws + (size_t)25165824);     // 16 MB each
  unsigned short* kw  = (unsigned short*)(ws + (size_t)41943040);
  unsigned short* vw  = (unsigned short*)(ws + (size_t)58720256);
  unsigned short* vtw = (unsigned short*)(ws + (size_t)75497472);     // ends at 92274688
  unsigned short* cw  = xb;   // concat aliases x_bf16 (dead after QKV GEMMs)
  unsigned short* mTb = vw;   // maskT (2 batches, 16MB) aliases vw (dead after k_transpose)

  // 1) conversions
  k_cvt<<<dim3(4096), dim3(256), 0, stream>>>(x, xb);
  k_cvt4<<<dim3(512, 4), dim3(256), 0, stream>>>(Wq, Wk, Wv, Wo, wqb, wkb, wvb, wob);
  // 2) QKV projections -> [B,H,S,dk] bf16
  k_gemm<0><<<dim3(8, 64, 3), dim3(256), 0, stream>>>(xb, wqb, wkb, wvb, bq, bk, bv,
                                                      (void*)qw, (void*)kw, (void*)vw);
  // 3) V -> V^T [B,H,dk,S]
  k_transpose<<<dim3(32, 16, 4), dim3(256), 0, stream>>>(vw, vtw);
  // 4) attention in two batch-pair rounds (maskT buffer = 16MB scratch)
  k_maskT<<<dim3(32, 32, 2), dim3(256), 0, stream>>>(mask, mTb, 0);
  k_attn2<<<dim3(16, 16, 2), dim3(256), 0, stream>>>(qw, kw, vtw, mTb, cw, 0);
  k_maskT<<<dim3(32, 32, 2), dim3(256), 0, stream>>>(mask, mTb, 2);
  k_attn2<<<dim3(16, 16, 2), dim3(256), 0, stream>>>(qw, kw, vtw, mTb, cw, 2);
  // 5) output projection -> fp32 d_out
  k_gemm<1><<<dim3(8, 64, 1), dim3(256), 0, stream>>>(cw, wob, wob, wob, bo, bo, bo,
                                                      d_out, d_out, d_out);
}

// Round 3
// 275.443 us; speedup vs baseline: 2.4081x; 2.4081x over previous
//
#include <hip/hip_runtime.h>

typedef __attribute__((ext_vector_type(8))) short s16x8;
typedef __attribute__((ext_vector_type(4))) float f32x4;
typedef __attribute__((ext_vector_type(16))) float f32x16;
typedef __attribute__((ext_vector_type(2))) unsigned int u32x2;

#define DEV static __device__ __forceinline__

// async global->LDS, 16B per lane. LDS dest must be uniform base + lane*16.
DEV void gload_lds16(const void* g, void* l) {
  __builtin_amdgcn_global_load_lds(
      (const __attribute__((address_space(1))) void*)g,
      (__attribute__((address_space(3))) void*)l, 16, 0, 0);
}

DEV unsigned short f2bf(float f) {  // RNE float->bf16 (no NaN inputs here)
  unsigned int u = __float_as_uint(f);
  u = (u + 0x7fffu + ((u >> 16) & 1u)) >> 16;
  return (unsigned short)u;
}

DEV unsigned pk2(float lo, float hi) {  // pack 2 f32 -> 2 bf16 in one VALU op
  unsigned r;
  asm("v_cvt_pk_bf16_f32 %0, %1, %2" : "=v"(r) : "v"(lo), "v"(hi));
  return r;
}

DEV float exp2_fast(float x) {  // v_exp_f32: 2^x
  float r;
  asm("v_exp_f32 %0, %1" : "=v"(r) : "v"(x));
  return r;
}

// ---------------- fp32 -> bf16 conversion ----------------
DEV void cvt8(const float* __restrict__ in, unsigned short* __restrict__ out, int i) {
  float4 a = *(const float4*)(in + i);
  float4 b = *(const float4*)(in + i + 4);
  union { s16x8 v; unsigned short u[8]; } o;
  o.u[0] = f2bf(a.x); o.u[1] = f2bf(a.y); o.u[2] = f2bf(a.z); o.u[3] = f2bf(a.w);
  o.u[4] = f2bf(b.x); o.u[5] = f2bf(b.y); o.u[6] = f2bf(b.z); o.u[7] = f2bf(b.w);
  *(s16x8*)(out + i) = o.v;
}

__global__ __launch_bounds__(256) void k_cvt(const float* __restrict__ in,
                                             unsigned short* __restrict__ out) {
  cvt8(in, out, (blockIdx.x * 256 + threadIdx.x) * 8);
}

__global__ __launch_bounds__(256) void k_cvt4(
    const float* __restrict__ a0, const float* __restrict__ a1,
    const float* __restrict__ a2, const float* __restrict__ a3,
    unsigned short* __restrict__ o0, unsigned short* __restrict__ o1,
    unsigned short* __restrict__ o2, unsigned short* __restrict__ o3) {
  const float* in; unsigned short* out;
  switch (blockIdx.y) {
    case 0: in = a0; out = o0; break;
    case 1: in = a1; out = o1; break;
    case 2: in = a2; out = o2; break;
    default: in = a3; out = o3; break;
  }
  cvt8(in, out, (blockIdx.x * 256 + threadIdx.x) * 8);
}

// ---------------- NT GEMM: C[M,N] = A[M,K] * W[N,K]^T + bias ----------------
template <int MODE>
__global__ __launch_bounds__(256) void k_gemm(
    const unsigned short* __restrict__ A,
    const unsigned short* __restrict__ B0, const unsigned short* __restrict__ B1,
    const unsigned short* __restrict__ B2,
    const float* __restrict__ bias0, const float* __restrict__ bias1,
    const float* __restrict__ bias2,
    void* __restrict__ out0, void* __restrict__ out1, void* __restrict__ out2) {
  constexpr int K = 1024;
  __shared__ unsigned short As[128 * 64];
  __shared__ unsigned short Bs[128 * 64];

  const int z = blockIdx.z;
  const unsigned short* Bw = (z == 0) ? B0 : (z == 1) ? B1 : B2;
  const float* bias = (z == 0) ? bias0 : (z == 1) ? bias1 : bias2;
  void* outp = (z == 0) ? out0 : (z == 1) ? out1 : out2;

  const int tid = threadIdx.x;
  const int lane = tid & 63;
  const int l15 = lane & 15, g = lane >> 4;
  const int w = tid >> 6;
  const int wr = w >> 1, wc = w & 1;
  const int m0 = blockIdx.y * 128;
  const int n0 = blockIdx.x * 128;

  const int sr = tid >> 3;
  const int sc = tid & 7;

  f32x4 acc[4][4] = {};

  for (int kt = 0; kt < K / 64; ++kt) {
#pragma unroll
    for (int i = 0; i < 4; ++i) {
      const int row = i * 32 + sr;
      gload_lds16(A + (size_t)(m0 + row) * K + kt * 64 + ((sc ^ (row & 7)) * 8),
                  (void*)(As + i * 2048 + tid * 8));
      gload_lds16(Bw + (size_t)(n0 + row) * K + kt * 64 + ((sc ^ (row & 7)) * 8),
                  (void*)(Bs + i * 2048 + tid * 8));
    }
    __syncthreads();
#pragma unroll
    for (int ks = 0; ks < 2; ++ks) {
      s16x8 af[4], bf[4];
#pragma unroll
      for (int i = 0; i < 4; ++i) {
        const int ra = wr * 64 + i * 16 + l15;
        af[i] = *(const s16x8*)(As + ra * 64 + (((ks * 4 + g) ^ (ra & 7)) * 8));
        const int rb = wc * 64 + i * 16 + l15;
        bf[i] = *(const s16x8*)(Bs + rb * 64 + (((ks * 4 + g) ^ (rb & 7)) * 8));
      }
#pragma unroll
      for (int i = 0; i < 4; ++i)
#pragma unroll
        for (int j = 0; j < 4; ++j)
          acc[i][j] = __builtin_amdgcn_mfma_f32_16x16x32_bf16(af[i], bf[j], acc[i][j], 0, 0, 0);
    }
    __syncthreads();
  }

#pragma unroll
  for (int j = 0; j < 4; ++j) {
    const int gcol = n0 + wc * 64 + j * 16 + l15;
    const float bv = bias[gcol];
#pragma unroll
    for (int i = 0; i < 4; ++i) {
#pragma unroll
      for (int r = 0; r < 4; ++r) {
        const int grow = m0 + wr * 64 + i * 16 + g * 4 + r;
        const float val = acc[i][j][r] + bv;
        if (MODE == 0) {
          const int bb = grow >> 11, s = grow & 2047;
          const int h = gcol >> 6, d = gcol & 63;
          ((unsigned short*)outp)[(((size_t)(bb * 16 + h) * 2048 + s) << 6) + d] = f2bf(val);
        } else {
          ((float*)outp)[(size_t)grow * 1024 + gcol] = val;
        }
      }
    }
  }
}

// ---------------- V transpose: [B,H,S,dk] -> [B,H,dk,S] ----------------
__global__ __launch_bounds__(256) void k_transpose(const unsigned short* __restrict__ v,
                                                   unsigned short* __restrict__ vt) {
  __shared__ unsigned short T[64 * 72];
  const int t = threadIdx.x;
  const size_t base = (size_t)(blockIdx.z * 16 + blockIdx.y) * 2048 * 64;
  const int s0 = blockIdx.x * 64;
  {
    const int srow = t >> 2, dc = (t & 3) * 16;
    const unsigned short* src = v + base + (size_t)(s0 + srow) * 64 + dc;
    *(s16x8*)(T + srow * 72 + dc) = *(const s16x8*)src;
    *(s16x8*)(T + srow * 72 + dc + 8) = *(const s16x8*)(src + 8);
  }
  __syncthreads();
  {
    const int drow = t >> 2, scc = (t & 3) * 16;
    union { s16x8 v8; unsigned short u[8]; } o0, o1;
#pragma unroll
    for (int e = 0; e < 8; ++e) o0.u[e] = T[(scc + e) * 72 + drow];
#pragma unroll
    for (int e = 0; e < 8; ++e) o1.u[e] = T[(scc + 8 + e) * 72 + drow];
    unsigned short* dst = vt + base + (size_t)drow * 2048 + s0 + scc;
    *(s16x8*)dst = o0.v8;
    *(s16x8*)(dst + 8) = o1.v8;
  }
}

// ---------------- mask transpose: mask[b][q][kv] f32 -> maskT[bz][kv][q] bf16 ----------------
// pre-scaled by 1/sqrt(dk) * log2(e) (softmax runs in base-2 domain)
__global__ __launch_bounds__(256) void k_maskT(const float* __restrict__ mask,
                                               unsigned short* __restrict__ mT, int b0) {
  constexpr float SC = 0.125f * 1.44269504f;
  __shared__ unsigned short T[64][65];
  const int t = threadIdx.x;
  const int bz = blockIdx.z;
  const float* mb = mask + (size_t)(b0 + bz) * 2048 * 2048;
  unsigned short* ob = mT + (size_t)bz * 2048 * 2048;
  const int q0 = blockIdx.y * 64, k0 = blockIdx.x * 64;
  const int r = t >> 2, c4 = (t & 3) * 16;
  {
    const float* src = mb + (size_t)(q0 + r) * 2048 + k0 + c4;
#pragma unroll
    for (int i = 0; i < 16; i += 4) {
      float4 v = *(const float4*)(src + i);
      T[r][c4 + i + 0] = f2bf(v.x * SC);
      T[r][c4 + i + 1] = f2bf(v.y * SC);
      T[r][c4 + i + 2] = f2bf(v.z * SC);
      T[r][c4 + i + 3] = f2bf(v.w * SC);
    }
  }
  __syncthreads();
  {
    union { s16x8 v8; unsigned short u[8]; } o0, o1;
#pragma unroll
    for (int e = 0; e < 8; ++e) o0.u[e] = T[c4 + e][r];
#pragma unroll
    for (int e = 0; e < 8; ++e) o1.u[e] = T[c4 + 8 + e][r];
    unsigned short* dst = ob + (size_t)(k0 + r) * 2048 + q0 + c4;
    *(s16x8*)dst = o0.v8;
    *(s16x8*)(dst + 8) = o1.v8;
  }
}

// ---------------- flash attention, swapped-QK^T 32x32, LDS-staged mask ----------------
// grid (H=16, S/128=16, 2 batches), 256 threads = 4 waves, each wave owns 32 q-rows.
// S^T = mfma_32x32x16(K, Q): lane q = q0+w*32+(lane&31); kv = 32f+(r&3)+8*(r>>2)+4*(lane>>5).
// K [kv][d], V^T [d][kv], maskT tile [kv][q] all double-buffered in LDS via global_load_lds
// with chunk^(row&7) swizzle (inverse applied on global source). Mask reads are ds_read_u16
// with compile-time immediate offsets off 8 precomputed base addresses.
__global__ __launch_bounds__(256) void k_attn3(
    const unsigned short* __restrict__ q, const unsigned short* __restrict__ k,
    const unsigned short* __restrict__ vt, const unsigned short* __restrict__ mT,
    unsigned short* __restrict__ concat, int b0) {
  __shared__ unsigned short Ks[2][64 * 64];    // 8KB each
  __shared__ unsigned short Vs[2][64 * 64];    // 8KB each
  __shared__ unsigned short Ms[2][64 * 128];   // 16KB each

  const int tid = threadIdx.x;
  const int lane = tid & 63;
  const int w = tid >> 6;
  const int l31 = lane & 31;
  const int hh = lane >> 5;
  const int h = blockIdx.x, qt = blockIdx.y, bz = blockIdx.z;
  const int b = b0 + bz;

  const size_t bhO = (size_t)(b * 16 + h) * (2048 * 64);
  const unsigned short* kb = k + bhO;
  const unsigned short* vb = vt + bhO;
  const int q0 = qt * 128;
  const int qc = w * 32 + l31;     // in-block q (0..127)
  const int qg = q0 + qc;          // global q row

  // Q B-fragments: qf[kd] holds Q[qg][kd*16 + hh*8 + i]
  s16x8 qf[4];
  {
    const unsigned short* qp = q + bhO + (size_t)qg * 64 + hh * 8;
#pragma unroll
    for (int kd = 0; kd < 4; ++kd) qf[kd] = *(const s16x8*)(qp + kd * 16);
  }

  const unsigned short* mtb = mT + (size_t)bz * (2048 * 2048);

  // mask LDS read bases: addr(shorts) = base[c] + (r>>2)*1024 + f*4096, c = r&3
  // derivation: kvrel = (r&3)+4hh+8(r>>2)+32f; chunk_l = A ^ (kvrel&7) = (A^4hh)^(r&3)
  const int A2 = (qc >> 3) ^ (hh << 2);
  const unsigned short* mpp[2][4];
#pragma unroll
  for (int bu = 0; bu < 2; ++bu)
#pragma unroll
    for (int c = 0; c < 4; ++c)
      mpp[bu][c] = Ms[bu] + (qc & 7) + hh * 512 + ((A2 ^ c) * 8) + c * 128;

  float m_r = -3.0e38f, l_r = 0.f;
  f32x16 oacc[2] = {};

  const int sr = tid >> 3;  // 0..31
  const int sc = tid & 7;

#define STAGE(BUF, T_)                                                              \
  {                                                                                 \
    const int kv0s = (T_)*64;                                                       \
    _Pragma("unroll") for (int i = 0; i < 2; ++i) {                                 \
      const int row = i * 32 + sr;                                                  \
      const int sz = (sc ^ (row & 7)) * 8;                                          \
      gload_lds16(kb + (size_t)(kv0s + row) * 64 + sz,                              \
                  (void*)(Ks[BUF] + i * 2048 + tid * 8));                           \
      gload_lds16(vb + (size_t)row * 2048 + kv0s + sz,                              \
                  (void*)(Vs[BUF] + i * 2048 + tid * 8));                           \
    }                                                                               \
    _Pragma("unroll") for (int j = 0; j < 4; ++j) {                                 \
      const int s = j * 256 + tid;                                                  \
      const int mrow = s >> 4, mch = s & 15;                                        \
      gload_lds16(mtb + (size_t)(kv0s + mrow) * 2048 + q0 + ((mch ^ (mrow & 7)) * 8), \
                  (void*)(Ms[BUF] + j * 2048 + tid * 8));                           \
    }                                                                               \
  }

  STAGE(0, 0)
  __syncthreads();  // compiler-emitted vmcnt(0) drains the stage

  for (int tt = 0; tt < 16; ++tt) {
#pragma unroll
    for (int half = 0; half < 2; ++half) {
      const int t = tt * 2 + half;
      if (t < 31) STAGE(half ^ 1, t + 1)

      // QK^T -> S^T [64 kv][32 q]
      f32x16 sacc[2] = {};
      __builtin_amdgcn_s_setprio(1);
#pragma unroll
      for (int f = 0; f < 2; ++f) {
        const int rk = f * 32 + l31;
        const unsigned short* Kr = Ks[half] + rk * 64;
        const int swb = rk & 7;
#pragma unroll
        for (int kd = 0; kd < 4; ++kd) {
          const s16x8 kf = *(const s16x8*)(Kr + (((kd * 2 + hh) ^ swb) * 8));
          sacc[f] = __builtin_amdgcn_mfma_f32_32x32x16_bf16(kf, qf[kd], sacc[f], 0, 0, 0);
        }
      }
      __builtin_amdgcn_s_setprio(0);

      // mask (pre-scaled bf16 in LDS) + online softmax (base-2), lane-local
      float p[32];
      float tm = -3.0e38f;
#pragma unroll
      for (int f = 0; f < 2; ++f)
#pragma unroll
        for (int r = 0; r < 16; ++r) {
          const unsigned short mu = mpp[half][r & 3][(r >> 2) * 1024 + f * 4096];
          const float mval = __uint_as_float((unsigned)mu << 16);
          const float sv = sacc[f][r] * mval;
          p[f * 16 + r] = sv;
          tm = fmaxf(tm, sv);
        }
      tm = fmaxf(tm, __shfl_xor(tm, 32, 64));
      if (__any(tm > m_r + 11.5f)) {  // T13 defer-max (11.5 log2-units = 8 nats)
        const float mn = fmaxf(m_r, tm);
        const float rs = exp2_fast(m_r - mn);
        m_r = mn;
        l_r *= rs;
#pragma unroll
        for (int df = 0; df < 2; ++df)
#pragma unroll
          for (int r = 0; r < 16; ++r) oacc[df][r] *= rs;
      }
      float ps = 0.f;
#pragma unroll
      for (int n = 0; n < 32; ++n) {
        p[n] = exp2_fast(p[n] - m_r);
        ps += p[n];
      }
      ps += __shfl_xor(ps, 32, 64);
      l_r += ps;

      // P^T -> bf16 B-frags (T12) + PV: oacc[df] += V^T * P^T
#pragma unroll
      for (int ks = 0; ks < 4; ++ks) {
        const int pb = ks * 8;
        const unsigned X0 = pk2(p[pb + 0], p[pb + 1]);
        const unsigned X1 = pk2(p[pb + 2], p[pb + 3]);
        const unsigned Y0 = pk2(p[pb + 4], p[pb + 5]);
        const unsigned Y1 = pk2(p[pb + 6], p[pb + 7]);
        const u32x2 r0 = __builtin_amdgcn_permlane32_swap(X0, Y0, false, false);
        const u32x2 r1 = __builtin_amdgcn_permlane32_swap(X1, Y1, false, false);
        union { s16x8 v; unsigned u[4]; } pf;
        pf.u[0] = r0.x; pf.u[1] = r1.x; pf.u[2] = r0.y; pf.u[3] = r1.y;
        __builtin_amdgcn_s_setprio(1);
#pragma unroll
        for (int df = 0; df < 2; ++df) {
          const int rv = df * 32 + l31;
          const s16x8 vf =
              *(const s16x8*)(Vs[half] + rv * 64 + (((ks * 2 + hh) ^ (rv & 7)) * 8));
          oacc[df] = __builtin_amdgcn_mfma_f32_32x32x16_bf16(vf, pf.v, oacc[df], 0, 0, 0);
        }
        __builtin_amdgcn_s_setprio(0);
      }
      __syncthreads();  // drains vmcnt (next-tile stage) + lgkm; protects buffers
    }
  }
#undef STAGE

  // normalize + write concat [B,S,H*dk] bf16 (paired 4B stores)
  const float inv = 1.0f / l_r;
  unsigned short* cb = concat + ((size_t)b * 2048 + qg) * 1024 + h * 64;
#pragma unroll
  for (int df = 0; df < 2; ++df)
#pragma unroll
    for (int r = 0; r < 16; r += 2) {
      const int d = df * 32 + (r & 3) + 8 * (r >> 2) + 4 * hh;
      const unsigned u = (unsigned)f2bf(oacc[df][r] * inv) |
                         ((unsigned)f2bf(oacc[df][r + 1] * inv) << 16);
      *(unsigned*)(cb + d) = u;
    }
}

// ---------------- launch ----------------
extern "C" void kernel_launch(void* const* d_in, const int* in_sizes, int n_in,
                              void* d_out, int out_size, void* d_ws, size_t ws_size,
                              hipStream_t stream) {
  const float* x    = (const float*)d_in[0];
  const float* mask = (const float*)d_in[1];
  const float* Wq   = (const float*)d_in[2];
  const float* bq   = (const float*)d_in[3];
  const float* Wk   = (const float*)d_in[4];
  const float* bk   = (const float*)d_in[5];
  const float* Wv   = (const float*)d_in[6];
  const float* bv   = (const float*)d_in[7];
  const float* Wo   = (const float*)d_in[8];
  const float* bo   = (const float*)d_in[9];

  char* ws = (char*)d_ws;
  unsigned short* xb  = (unsigned short*)(ws);                        // 16 MB (x bf16; later aliased by concat)
  unsigned short* wqb = (unsigned short*)(ws + (size_t)16777216);     // 2 MB each
  unsigned short* wkb = (unsigned short*)(ws + (size_t)18874368);
  unsigned short* wvb = (unsigned short*)(ws + (size_t)20971520);
  unsigned short* wob = (unsigned short*)(ws + (size_t)23068672);
  unsigned short* qw  = (unsigned short*)(ws + (size_t)25165824);     // 16 MB each
  unsigned short* kw  = (unsigned short*)(ws + (size_t)41943040);
  unsigned short* vw  = (unsigned short*)(ws + (size_t)58720256);
  unsigned short* vtw = (unsigned short*)(ws + (size_t)75497472);     // ends at 92274688
  unsigned short* cw  = xb;   // concat aliases x_bf16 (dead after QKV GEMMs)
  unsigned short* mTb = vw;   // maskT (2 batches, 16MB) aliases vw (dead after k_transpose)

  // 1) conversions
  k_cvt<<<dim3(4096), dim3(256), 0, stream>>>(x, xb);
  k_cvt4<<<dim3(512, 4), dim3(256), 0, stream>>>(Wq, Wk, Wv, Wo, wqb, wkb, wvb, wob);
  // 2) QKV projections -> [B,H,S,dk] bf16
  k_gemm<0><<<dim3(8, 64, 3), dim3(256), 0, stream>>>(xb, wqb, wkb, wvb, bq, bk, bv,
                                                      (void*)qw, (void*)kw, (void*)vw);
  // 3) V -> V^T [B,H,dk,S]
  k_transpose<<<dim3(32, 16, 4), dim3(256), 0, stream>>>(vw, vtw);
  // 4) attention in two batch-pair rounds (maskT buffer = 16MB scratch)
  k_maskT<<<dim3(32, 32, 2), dim3(256), 0, stream>>>(mask, mTb, 0);
  k_attn3<<<dim3(16, 16, 2), dim3(256), 0, stream>>>(qw, kw, vtw, mTb, cw, 0);
  k_maskT<<<dim3(32, 32, 2), dim3(256), 0, stream>>>(mask, mTb, 2);
  k_attn3<<<dim3(16, 16, 2), dim3(256), 0, stream>>>(qw, kw, vtw, mTb, cw, 2);
  // 5) output projection -> fp32 d_out
  k_gemm<1><<<dim3(8, 64, 1), dim3(256), 0, stream>>>(cw, wob, wob, wob, bo, bo, bo,
                                                      d_out, d_out, d_out);
}